// Round 7
// baseline (9068.974 us; speedup 1.0000x reference)
//
#include <hip/hip_runtime.h>
#include <math.h>

#define BB 128
#define TT 256
#define DD 512
#define HH 1024
#define G4H 4096
#define CO 7
#define XROW (TT * DD)      // x row stride per batch (fp32 elements)
#define LOOFF (BB * HH)     // offset of lo-plane within an h slot (elements)

typedef __attribute__((ext_vector_type(8))) short bf16x8;
typedef __attribute__((ext_vector_type(4))) float f32x4;
typedef __attribute__((ext_vector_type(16))) float f32x16;

__device__ __forceinline__ unsigned short f2bf(float f) {
  unsigned int u = __float_as_uint(f);
  unsigned int r = (u + 0x7fffu + ((u >> 16) & 1u)) >> 16;
  return (unsigned short)r;
}
__device__ __forceinline__ float bf2f(unsigned short h) {
  return __uint_as_float(((unsigned int)h) << 16);
}
__device__ __forceinline__ float tanh_fast(float x) {
  x = fminf(fmaxf(x, -15.f), 15.f);
  const float e = __expf(2.f * x);
  return (e - 1.f) / (e + 1.f);
}
__device__ __forceinline__ float sigmoid_fast(float x) {
  return 1.f / (1.f + __expf(-x));
}
__device__ __forceinline__ void split8(float4 a, float4 b, bf16x8& hi, bf16x8& lo) {
  float f[8] = {a.x, a.y, a.z, a.w, b.x, b.y, b.z, b.w};
  unsigned short h8[8], l8[8];
#pragma unroll
  for (int e = 0; e < 8; ++e) {
    const unsigned short hh = f2bf(f[e]);
    h8[e] = hh;
    l8[e] = f2bf(f[e] - bf2f(hh));
  }
  hi = *(bf16x8*)h8;
  lo = *(bf16x8*)l8;
}

// ------------------------------------------------------------------
// Pack concatenated weights [Wh | Wx] into 32x32x16 B-fragment-major
// bf16 hi/lo, gate-interleaved n-perm: srow(n)=(n&3)*1024+(n>>6)*16+((n>>2)&15)
// frag element: pk[(nt*KS + ks)*1024 + hilo*512 + l*8 + e] =
//   src[srow(nt*32 + (l&31))][ks*16 + (l>>5)*8 + e]     (ushort units)
// ------------------------------------------------------------------
__global__ __launch_bounds__(256)
void pack_w3(const float* __restrict__ Wh, const float* __restrict__ Wx,
             unsigned short* __restrict__ pk, int Kh, int Kx) {
  const int KS = (Kh + Kx) >> 4;
  const int idx = blockIdx.x * 256 + threadIdx.x;
  const int total = 128 * KS * 64;
  if (idx >= total) return;
  const int l = idx & 63;
  const int t2 = idx >> 6;
  const int ks = t2 % KS;
  const int nt = t2 / KS;
  const int n = (nt << 5) + (l & 31);
  const int srow = ((n & 3) << 10) + ((n >> 6) << 4) + ((n >> 2) & 15);
  const int col = (ks << 4) + ((l >> 5) << 3);
  const float* src = (col < Kh) ? (Wh + (size_t)srow * Kh + col)
                                : (Wx + (size_t)srow * Kx + (col - Kh));
  unsigned short hi[8], lo[8];
#pragma unroll
  for (int e = 0; e < 8; ++e) {
    const float v = src[e];
    const unsigned short h = f2bf(v);
    hi[e] = h;
    lo[e] = f2bf(v - bf2f(h));
  }
  const size_t base = ((size_t)nt * KS + ks) * 1024 + (size_t)l * 8;
  *(uint4*)(pk + base) = *(const uint4*)hi;
  *(uint4*)(pk + base + 512) = *(const uint4*)lo;
}

// LDS buffer layout (40960 B per buffer, two buffers):
//  [0, 8192):      W block: ks_l*2048 + hilo*1024 + l*16
//  [8192, 24576):  A hi bf16: row*128 + ((slot ^ (row&7))<<4), slot=k16*2+khalf
//  [24576, 40960): A lo bf16 (same addressing)
//  (x blocks: [8192, 40960): fp32 row*256 + ((unit ^ (row&7))<<5))

__device__ __forceinline__ void comp_h32(const char* buf, int kq, int l, int l31, int lh, int mh,
                                         f32x16& acc0, f32x16& acc1) {
  const bf16x8 wh = *(const bf16x8*)(buf + kq * 2048 + l * 16);
  const bf16x8 wl = *(const bf16x8*)(buf + kq * 2048 + 1024 + l * 16);
  const int sw = (((kq << 1) + lh) ^ (l31 & 7)) << 4;
  const char* a0 = buf + 8192 + ((mh << 6) + l31) * 128 + sw;
  const char* a1 = a0 + 32 * 128;
  const bf16x8 ah0 = *(const bf16x8*)a0;
  const bf16x8 al0 = *(const bf16x8*)(a0 + 16384);
  const bf16x8 ah1 = *(const bf16x8*)a1;
  const bf16x8 al1 = *(const bf16x8*)(a1 + 16384);
  acc0 = __builtin_amdgcn_mfma_f32_32x32x16_bf16(ah0, wh, acc0, 0, 0, 0);
  acc0 = __builtin_amdgcn_mfma_f32_32x32x16_bf16(ah0, wl, acc0, 0, 0, 0);
  acc0 = __builtin_amdgcn_mfma_f32_32x32x16_bf16(al0, wh, acc0, 0, 0, 0);
  acc1 = __builtin_amdgcn_mfma_f32_32x32x16_bf16(ah1, wh, acc1, 0, 0, 0);
  acc1 = __builtin_amdgcn_mfma_f32_32x32x16_bf16(ah1, wl, acc1, 0, 0, 0);
  acc1 = __builtin_amdgcn_mfma_f32_32x32x16_bf16(al1, wh, acc1, 0, 0, 0);
}

__device__ __forceinline__ void comp_x32(const char* buf, int kq, int l, int l31, int lh, int mh,
                                         f32x16& acc0, f32x16& acc1) {
  const bf16x8 wh = *(const bf16x8*)(buf + kq * 2048 + l * 16);
  const bf16x8 wl = *(const bf16x8*)(buf + kq * 2048 + 1024 + l * 16);
  const int sw = (((kq << 1) + lh) ^ (l31 & 7)) << 5;
  const char* a0 = buf + 8192 + ((mh << 6) + l31) * 256 + sw;
  const char* a1 = a0 + 32 * 256;
  bf16x8 ah, al;
  split8(*(const float4*)a0, *(const float4*)(a0 + 16), ah, al);
  acc0 = __builtin_amdgcn_mfma_f32_32x32x16_bf16(ah, wh, acc0, 0, 0, 0);
  acc0 = __builtin_amdgcn_mfma_f32_32x32x16_bf16(ah, wl, acc0, 0, 0, 0);
  acc0 = __builtin_amdgcn_mfma_f32_32x32x16_bf16(al, wh, acc0, 0, 0, 0);
  split8(*(const float4*)a1, *(const float4*)(a1 + 16), ah, al);
  acc1 = __builtin_amdgcn_mfma_f32_32x32x16_bf16(ah, wh, acc1, 0, 0, 0);
  acc1 = __builtin_amdgcn_mfma_f32_32x32x16_bf16(ah, wl, acc1, 0, 0, 0);
  acc1 = __builtin_amdgcn_mfma_f32_32x32x16_bf16(al, wh, acc1, 0, 0, 0);
}

// ------------------------------------------------------------------
// Diagonal dual-layer step, dedup'd: WGs 0..127 = layer0 @ t (q = WG, 32 cols,
// all 128 rows), WGs 128..255 = layer1 @ t-1. 512 thr = 8 waves:
// mh = wid&1 (64-row half), kq = wid>>1 (k16 slices s with s&3==kq).
// 32x32x16 MFMA; K-split partials reduced through LDS at the end.
// ------------------------------------------------------------------
__global__ __launch_bounds__(512, 1)
void step_dual(int t,
               const float* __restrict__ x,
               const unsigned short* __restrict__ pk0,
               const unsigned short* __restrict__ pk1,
               unsigned short* __restrict__ h0s0, unsigned short* __restrict__ h0s1,
               unsigned short* __restrict__ h1s0, unsigned short* __restrict__ h1s1,
               const float* __restrict__ bih0, const float* __restrict__ bhh0,
               const float* __restrict__ bih1, const float* __restrict__ bhh1,
               float* __restrict__ c0, float* __restrict__ c1) {
  __shared__ __align__(16) char lds[81920];
  char* const buf0 = lds;
  char* const buf1 = lds + 40960;
  const int bid = blockIdx.x;
  const int layer = bid >> 7;
  if (layer == 0 && t >= TT) return;
  if (layer == 1 && t < 1) return;
  const int q = bid & 127;
  const int tid = threadIdx.x;
  const int wid = tid >> 6, l = tid & 63;
  const int mh = wid & 1, kq = wid >> 1;
  const int l31 = l & 31, lh = l >> 5;

  const int KS16 = layer ? 128 : 96;
  const int NB = layer ? 32 : 24;
  const unsigned short* pk = layer ? pk1 : pk0;
  const unsigned short* a1;          // prev-h of own layer (hi; lo at +LOOFF)
  const unsigned short* a2;          // layer1: h0[t-1]
  unsigned short* ho;
  float* cb;
  const float* bv0;
  const float* bv1;
  if (layer == 0) {
    a1 = (t & 1) ? h0s0 : h0s1;
    ho = (t & 1) ? h0s1 : h0s0;
    a2 = a1;
    cb = c0; bv0 = bih0; bv1 = bhh0;
  } else {
    const int u = t - 1;
    a1 = (u & 1) ? h1s0 : h1s1;
    ho = (u & 1) ? h1s1 : h1s0;
    a2 = (t & 1) ? h0s0 : h0s1;
    cb = c1; bv0 = bih1; bv1 = bhh1;
  }

  // staging maps (thread = one row, 1/4 of its k-range)
  const int srow_ = tid >> 2;        // 0..127
  const int sub = tid & 3;
  const int r7 = srow_ & 7;
  const unsigned short* a1g = a1 + (size_t)srow_ * HH;
  const unsigned short* a2g = a2 + (size_t)srow_ * HH;
  const float* xg = x + (size_t)t * DD + (size_t)srow_ * XROW;
  const unsigned short* pkq = pk + (size_t)q * KS16 * 1024;

  const int ad0 = 8192 + srow_ * 128 + ((((sub << 1) + 0) ^ r7) << 4);
  const int ad1 = 8192 + srow_ * 128 + ((((sub << 1) + 1) ^ r7) << 4);
  const int xd0 = 8192 + srow_ * 256 + ((((sub << 1) + 0) ^ r7) << 5);
  const int xd1 = 8192 + srow_ * 256 + ((((sub << 1) + 1) ^ r7) << 5);

  f32x16 acc0 = (f32x16)(0.f), acc1 = (f32x16)(0.f);
  uint4 qw, qa0, qa1, qa2, qa3;

#define LOADW(bb) do { qw = *(const uint4*)(pkq + (size_t)(bb) * 4096 + tid * 8); } while (0)

#define LOADA(bb) do {                                                          \
    if ((bb) < 16) {                                                            \
      const unsigned short* s_ = a1g + ((bb) << 6) + (sub << 4);                \
      qa0 = *(const uint4*)s_;           qa1 = *(const uint4*)(s_ + 8);         \
      qa2 = *(const uint4*)(s_ + LOOFF); qa3 = *(const uint4*)(s_ + LOOFF + 8); \
    } else if (layer == 1) {                                                    \
      const unsigned short* s_ = a2g + (((bb) - 16) << 6) + (sub << 4);         \
      qa0 = *(const uint4*)s_;           qa1 = *(const uint4*)(s_ + 8);         \
      qa2 = *(const uint4*)(s_ + LOOFF); qa3 = *(const uint4*)(s_ + LOOFF + 8); \
    } else {                                                                    \
      const float* s_ = xg + (((bb) - 16) << 6) + (sub << 4);                   \
      qa0 = *(const uint4*)s_;        qa1 = *(const uint4*)(s_ + 4);            \
      qa2 = *(const uint4*)(s_ + 8);  qa3 = *(const uint4*)(s_ + 12);           \
    }                                                                           \
  } while (0)

#define WRITEB(buf, bb) do {                                                    \
    *(uint4*)((buf) + tid * 16) = qw;                                           \
    if ((bb) < 16 || layer == 1) {                                              \
      *(uint4*)((buf) + ad0) = qa0; *(uint4*)((buf) + ad1) = qa1;               \
      *(uint4*)((buf) + ad0 + 16384) = qa2; *(uint4*)((buf) + ad1 + 16384) = qa3; \
    } else {                                                                    \
      *(uint4*)((buf) + xd0) = qa0; *(uint4*)((buf) + xd0 + 16) = qa1;          \
      *(uint4*)((buf) + xd1) = qa2; *(uint4*)((buf) + xd1 + 16) = qa3;          \
    }                                                                           \
  } while (0)

  // prologue
  LOADW(0); LOADA(0);
  WRITEB(buf0, 0);
  __syncthreads();

  for (int b = 0; b < NB; ++b) {
    char* cur = (b & 1) ? buf1 : buf0;
    char* nxt = (b & 1) ? buf0 : buf1;
    if (b + 1 < NB) { LOADW(b + 1); LOADA(b + 1); }
    if (b < 16 || layer == 1) comp_h32(cur, kq, l, l31, lh, mh, acc0, acc1);
    else                      comp_x32(cur, kq, l, l31, lh, mh, acc0, acc1);
    if (b + 1 < NB) WRITEB(nxt, b + 1);
    __syncthreads();
  }
#undef LOADW
#undef LOADA
#undef WRITEB

  // ---- K-split reduction via LDS (reuses staging region) ----
  float* part = (float*)lds;   // [wid][tile][reg][lane] = ((wid*2+tile)*16+r)*64+l
#pragma unroll
  for (int r = 0; r < 16; ++r) part[(((wid << 1) + 0) * 16 + r) * 64 + l] = acc0[r];
#pragma unroll
  for (int r = 0; r < 16; ++r) part[(((wid << 1) + 1) * 16 + r) * 64 + l] = acc1[r];
  __syncthreads();

  // wave (mh,kq) handles regs [kq*4, kq*4+4) of both tiles
  const int n_ = (q << 5) + l31;
  const int srn = ((n_ & 3) << 10) + ((n_ >> 6) << 4) + ((n_ >> 2) & 15);
  const float bn = bv0[srn] + bv1[srn];
  const int j = (q << 3) + (l31 >> 2);
#pragma unroll
  for (int tile = 0; tile < 2; ++tile) {
#pragma unroll
    for (int rr = 0; rr < 4; ++rr) {
      const int r = (kq << 2) + rr;
      float v = bn;
#pragma unroll
      for (int k2 = 0; k2 < 4; ++k2)
        v += part[((((k2 << 1) + mh) << 1 | tile) * 16 + r) * 64 + l];
      const float v1 = __shfl_xor(v, 1);
      const float v2 = __shfl_xor(v, 2);
      const float v3 = __shfl_xor(v, 3);
      if ((l & 3) == 0) {
        const int row = (mh << 6) + (tile << 5) + (r & 3) + ((r >> 2) << 3) + (lh << 2);
        const float si = sigmoid_fast(v);
        const float sf = sigmoid_fast(v1);
        const float tg = tanh_fast(v2);
        const float so = sigmoid_fast(v3);
        const size_t ci = (size_t)row * HH + j;
        const float cn = sf * cb[ci] + si * tg;
        cb[ci] = cn;
        const float h = so * tanh_fast(cn);
        const unsigned short hh2 = f2bf(h);
        ho[(size_t)row * HH + j] = hh2;
        ho[LOOFF + (size_t)row * HH + j] = f2bf(h - bf2f(hh2));
      }
    }
  }
}

// ------------------------------------------------------------------
// FC from hi/lo h slot
// ------------------------------------------------------------------
__global__ __launch_bounds__(256)
void fc_hilo(const unsigned short* __restrict__ hhi, const unsigned short* __restrict__ hlo,
             const float* __restrict__ fcw, const float* __restrict__ fcb,
             float* __restrict__ out) {
  const int gw = (int)((blockIdx.x * 256 + threadIdx.x) >> 6);
  const int lane = threadIdx.x & 63;
  const int b = gw / CO;
  const int n = gw - b * CO;
  const unsigned short* hp = hhi + (size_t)b * HH;
  const unsigned short* lp = hlo + (size_t)b * HH;
  const float* wp = fcw + (size_t)n * HH;
  float s = 0.f;
  for (int k = lane; k < HH; k += 64) s += (bf2f(hp[k]) + bf2f(lp[k])) * wp[k];
#pragma unroll
  for (int off = 32; off; off >>= 1) s += __shfl_down(s, off);
  if (lane == 0) out[b * CO + n] = s + fcb[n];
}

// ==================================================================
// Fallback fp32 path (round-2 kernels, used only if ws_size is small)
// ==================================================================
__global__ __launch_bounds__(256)
void gemm_bias(const float* __restrict__ A, long long sOut, long long sIn, int lt,
               const float* __restrict__ W,
               const float* __restrict__ b0, const float* __restrict__ b1,
               float* __restrict__ C, int N, int K) {
  __shared__ float as[16][64];
  __shared__ float wsh[16][64];
  const int tid = threadIdx.x;
  const int bm = blockIdx.y << 6;
  const int bn = blockIdx.x << 6;
  const int tr = (tid >> 4) << 2;
  const int tc = (tid & 15) << 2;
  const int lrow = tid >> 2;
  const int lk4 = (tid & 3) << 2;
  const int msk = (1 << lt) - 1;
  const int r = bm + lrow;
  const float* ap = A + (size_t)(r >> lt) * sOut + (size_t)(r & msk) * sIn + lk4;
  const float* wp = W + (size_t)(bn + lrow) * K + lk4;
  float acc[4][4] = {};
  for (int k0 = 0; k0 < K; k0 += 16) {
    const float4 av = *(const float4*)(ap + k0);
    const float4 wv = *(const float4*)(wp + k0);
    __syncthreads();
    as[lk4 + 0][lrow] = av.x; as[lk4 + 1][lrow] = av.y;
    as[lk4 + 2][lrow] = av.z; as[lk4 + 3][lrow] = av.w;
    wsh[lk4 + 0][lrow] = wv.x; wsh[lk4 + 1][lrow] = wv.y;
    wsh[lk4 + 2][lrow] = wv.z; wsh[lk4 + 3][lrow] = wv.w;
    __syncthreads();
#pragma unroll
    for (int k = 0; k < 16; ++k) {
      const float4 a = *(const float4*)&as[k][tr];
      const float4 b = *(const float4*)&wsh[k][tc];
      acc[0][0] += a.x * b.x; acc[0][1] += a.x * b.y; acc[0][2] += a.x * b.z; acc[0][3] += a.x * b.w;
      acc[1][0] += a.y * b.x; acc[1][1] += a.y * b.y; acc[1][2] += a.y * b.z; acc[1][3] += a.y * b.w;
      acc[2][0] += a.z * b.x; acc[2][1] += a.z * b.y; acc[2][2] += a.z * b.z; acc[2][3] += a.z * b.w;
      acc[3][0] += a.w * b.x; acc[3][1] += a.w * b.y; acc[3][2] += a.w * b.z; acc[3][3] += a.w * b.w;
    }
  }
  const float* bp0 = b0 + bn + tc;
  const float* bp1 = b1 + bn + tc;
#pragma unroll
  for (int i = 0; i < 4; ++i) {
    float* cp = C + (size_t)(bm + tr + i) * N + bn + tc;
#pragma unroll
    for (int j = 0; j < 4; ++j) cp[j] = acc[i][j] + bp0[j] + bp1[j];
  }
}

__global__ __launch_bounds__(256)
void lstm_step(const float* __restrict__ gx, long long gxstride,
               const float* __restrict__ whh,
               const float* __restrict__ hprev, long long pstride,
               float* __restrict__ hnext, long long nstride,
               float* __restrict__ cbuf) {
  __shared__ float hs[32][16];
  __shared__ float wsm[32][4][32];
  const int tid = threadIdx.x;
  const int jt = blockIdx.x << 5;
  const int bm = blockIdx.y << 4;
  const int col = tid & 31;
  const int rp = (tid >> 5) << 1;
  const int hr = tid >> 4;
  const int hk = (tid & 15) << 1;
  const int wrow = tid & 127;
  const int wg = wrow >> 5;
  const int wc = wrow & 31;
  const int wk = (tid >> 7) << 4;
  const float* wbase = whh + (size_t)(wg * HH + jt + wc) * HH + wk;
  const float* hbase = hprev + (size_t)(bm + hr) * pstride + hk;

  float acc[4][2] = {};
  for (int k0 = 0; k0 < HH; k0 += 32) {
    const float2 hv = *(const float2*)(hbase + k0);
    const float4 wv0 = *(const float4*)(wbase + k0);
    const float4 wv1 = *(const float4*)(wbase + k0 + 4);
    const float4 wv2 = *(const float4*)(wbase + k0 + 8);
    const float4 wv3 = *(const float4*)(wbase + k0 + 12);
    __syncthreads();
    hs[hk][hr] = hv.x; hs[hk + 1][hr] = hv.y;
    {
      const float wvv[16] = {wv0.x, wv0.y, wv0.z, wv0.w, wv1.x, wv1.y, wv1.z, wv1.w,
                             wv2.x, wv2.y, wv2.z, wv2.w, wv3.x, wv3.y, wv3.z, wv3.w};
#pragma unroll
      for (int i = 0; i < 16; ++i) wsm[wk + i][wg][wc] = wvv[i];
    }
    __syncthreads();
#pragma unroll
    for (int k = 0; k < 32; ++k) {
      const float2 a = *(const float2*)&hs[k][rp];
      const float wi = wsm[k][0][col];
      const float wf = wsm[k][1][col];
      const float wg_ = wsm[k][2][col];
      const float wo = wsm[k][3][col];
      acc[0][0] += a.x * wi;  acc[0][1] += a.y * wi;
      acc[1][0] += a.x * wf;  acc[1][1] += a.y * wf;
      acc[2][0] += a.x * wg_; acc[2][1] += a.y * wg_;
      acc[3][0] += a.x * wo;  acc[3][1] += a.y * wo;
    }
  }
#pragma unroll
  for (int rr = 0; rr < 2; ++rr) {
    const int b = bm + rp + rr;
    const int j = jt + col;
    const size_t gxo = (size_t)b * gxstride + j;
    const float gi = acc[0][rr] + gx[gxo];
    const float gf = acc[1][rr] + gx[gxo + HH];
    const float gg = acc[2][rr] + gx[gxo + 2 * HH];
    const float go = acc[3][rr] + gx[gxo + 3 * HH];
    const float si = 1.f / (1.f + expf(-gi));
    const float sf = 1.f / (1.f + expf(-gf));
    const float so = 1.f / (1.f + expf(-go));
    const size_t cidx = (size_t)b * HH + j;
    const float cn = sf * cbuf[cidx] + si * tanhf(gg);
    cbuf[cidx] = cn;
    hnext[(size_t)b * nstride + j] = so * tanhf(cn);
  }
}

__global__ __launch_bounds__(256)
void fc_kernel(const float* __restrict__ hlast, const float* __restrict__ fcw,
               const float* __restrict__ fcb, float* __restrict__ out) {
  const int gw = (int)((blockIdx.x * 256 + threadIdx.x) >> 6);
  const int lane = threadIdx.x & 63;
  const int b = gw / CO;
  const int n = gw - b * CO;
  const float* hp = hlast + (size_t)b * HH;
  const float* wp = fcw + (size_t)n * HH;
  float s = 0.f;
  for (int k = lane; k < HH; k += 64) s += hp[k] * wp[k];
#pragma unroll
  for (int off = 32; off; off >>= 1) s += __shfl_down(s, off);
  if (lane == 0) out[b * CO + n] = s + fcb[n];
}

// ==================================================================
extern "C" void kernel_launch(void* const* d_in, const int* in_sizes, int n_in,
                              void* d_out, int out_size, void* d_ws, size_t ws_size,
                              hipStream_t stream) {
  const float* x    = (const float*)d_in[0];
  const float* wih0 = (const float*)d_in[1];
  const float* whh0 = (const float*)d_in[2];
  const float* bih0 = (const float*)d_in[3];
  const float* bhh0 = (const float*)d_in[4];
  const float* wih1 = (const float*)d_in[5];
  const float* whh1 = (const float*)d_in[6];
  const float* bih1 = (const float*)d_in[7];
  const float* bhh1 = (const float*)d_in[8];
  const float* fcw  = (const float*)d_in[9];
  const float* fcb  = (const float*)d_in[10];
  float* out = (float*)d_out;

  // ---- MFMA-path workspace ----
  const size_t pk0B  = (size_t)128 * 96 * 2048;       // 25,165,824 B
  const size_t pk1B  = (size_t)128 * 128 * 2048;      // 33,554,432 B
  const size_t slotB = 2 * (size_t)BB * HH * 2;       // 524,288 B (hi+lo)
  const size_t cB    = (size_t)BB * HH * 4;           // 524,288 B
  const size_t needB = pk0B + pk1B + 4 * slotB + 2 * cB;  // 61,865,984 B

  if (needB <= ws_size) {
    char* p = (char*)d_ws;
    unsigned short* pk0  = (unsigned short*)p; p += pk0B;
    unsigned short* pk1  = (unsigned short*)p; p += pk1B;
    unsigned short* h0s0 = (unsigned short*)p; p += slotB;
    unsigned short* h1s0 = (unsigned short*)p; p += slotB;
    char* zblock = p;                         // h0s1, h1s1, c0, c1 (zeroed)
    unsigned short* h0s1 = (unsigned short*)p; p += slotB;
    unsigned short* h1s1 = (unsigned short*)p; p += slotB;
    float* c0 = (float*)p; p += cB;
    float* c1 = (float*)p; p += cB;

    hipMemsetAsync(zblock, 0, 2 * slotB + 2 * cB, stream);

    pack_w3<<<dim3((128 * 96 * 64 + 255) / 256), 256, 0, stream>>>(whh0, wih0, pk0, HH, DD);
    pack_w3<<<dim3((128 * 128 * 64 + 255) / 256), 256, 0, stream>>>(whh1, wih1, pk1, HH, HH);

    for (int t = 0; t <= TT; ++t) {
      step_dual<<<dim3(256), 512, 0, stream>>>(t, x, pk0, pk1,
                                               h0s0, h0s1, h1s0, h1s1,
                                               bih0, bhh0, bih1, bhh1, c0, c1);
    }

    // final u = 255 (odd) wrote slot[1] = h1s1
    fc_hilo<<<dim3((BB * CO * 64) / 256), 256, 0, stream>>>(h1s1, h1s1 + LOOFF,
                                                            fcw, fcb, out);
    return;
  }

  // ---------------- fallback fp32 path ----------------
  {
    int Tc2 = 64, lt2 = 6;
    while (Tc2 > 1) {
      size_t need = ((size_t)655360 * (size_t)Tc2 + 4u * 131072u + 1024u) * 4u;
      if (need <= ws_size) break;
      Tc2 >>= 1; --lt2;
    }
    float* ws  = (float*)d_ws;
    float* gxc = ws;
    float* hc  = gxc + (size_t)BB * Tc2 * G4H;
    float* c0  = hc + (size_t)BB * Tc2 * HH;
    float* c1  = c0 + (size_t)BB * HH;
    float* h2a = c1 + (size_t)BB * HH;
    float* h2b = h2a + (size_t)BB * HH;
    float* zb  = h2b + (size_t)BB * HH;

    hipMemsetAsync(zb, 0, HH * sizeof(float), stream);
    hipMemsetAsync(c0, 0, (size_t)BB * HH * sizeof(float), stream);
    hipMemsetAsync(c1, 0, (size_t)BB * HH * sizeof(float), stream);

    const dim3 gGemm(G4H / 64, (BB * Tc2) / 64);
    const dim3 gStep(HH / 32, BB / 16);
    const long long gxs = (long long)Tc2 * G4H;
    const long long hcs = (long long)Tc2 * HH;

    const int nChunks = TT / Tc2;
    for (int ci = 0; ci < nChunks; ++ci) {
      const int t0 = ci * Tc2;
      gemm_bias<<<gGemm, 256, 0, stream>>>(x + (size_t)t0 * DD, (long long)TT * DD,
                                           (long long)DD, lt2, wih0, bih0, bhh0,
                                           gxc, G4H, DD);
      for (int tl = 0; tl < Tc2; ++tl) {
        const int t = t0 + tl;
        const float* hprev;
        long long ps;
        if (t == 0) { hprev = zb; ps = 0; }
        else {
          const int ptl = (tl == 0) ? (Tc2 - 1) : (tl - 1);
          hprev = hc + (size_t)ptl * HH; ps = hcs;
        }
        lstm_step<<<gStep, 256, 0, stream>>>(gxc + (size_t)tl * G4H, gxs, whh0,
                                             hprev, ps, hc + (size_t)tl * HH, hcs, c0);
      }
      gemm_bias<<<gGemm, 256, 0, stream>>>(hc, hcs, (long long)HH, lt2,
                                           wih1, bih1, bhh1, gxc, G4H, HH);
      for (int tl = 0; tl < Tc2; ++tl) {
        const int t = t0 + tl;
        const float* hprev;
        long long ps;
        if (t == 0) { hprev = zb; ps = 0; }
        else { hprev = ((t - 1) & 1) ? h2b : h2a; ps = HH; }
        float* hnext = (t & 1) ? h2b : h2a;
        lstm_step<<<gStep, 256, 0, stream>>>(gxc + (size_t)tl * G4H, gxs, whh1,
                                             hprev, ps, hnext, HH, c1);
      }
    }
    fc_kernel<<<dim3((BB * CO * 64) / 256), 256, 0, stream>>>(h2b, fcw, fcb, out);
  }
}

// Round 8
// 7326.612 us; speedup vs baseline: 1.2378x; 1.2378x over previous
//
#include <hip/hip_runtime.h>
#include <math.h>

#define BB 128
#define TT 256
#define DD 512
#define HH 1024
#define G4H 4096
#define CO 7
#define XROW (TT * DD)      // x row stride per batch (fp32 elements)
#define LOOFF (BB * HH)     // offset of lo-plane within an h slot (elements)

typedef __attribute__((ext_vector_type(8))) short bf16x8;
typedef __attribute__((ext_vector_type(4))) float f32x4;

__device__ __forceinline__ unsigned short f2bf(float f) {
  unsigned int u = __float_as_uint(f);
  unsigned int r = (u + 0x7fffu + ((u >> 16) & 1u)) >> 16;
  return (unsigned short)r;
}
__device__ __forceinline__ float bf2f(unsigned short h) {
  return __uint_as_float(((unsigned int)h) << 16);
}
__device__ __forceinline__ float tanh_fast(float x) {
  x = fminf(fmaxf(x, -15.f), 15.f);
  const float e = __expf(2.f * x);
  return (e - 1.f) / (e + 1.f);
}
__device__ __forceinline__ float sigmoid_fast(float x) {
  return 1.f / (1.f + __expf(-x));
}
__device__ __forceinline__ void split8(float4 a, float4 b, bf16x8& hi, bf16x8& lo) {
  float f[8] = {a.x, a.y, a.z, a.w, b.x, b.y, b.z, b.w};
  unsigned short h8[8], l8[8];
#pragma unroll
  for (int e = 0; e < 8; ++e) {
    const unsigned short hh = f2bf(f[e]);
    h8[e] = hh;
    l8[e] = f2bf(f[e] - bf2f(hh));
  }
  hi = *(bf16x8*)h8;
  lo = *(bf16x8*)l8;
}

// raw barrier: drain only LDS queue (ds_write visibility), keep global loads
// in flight (no vmcnt drain — compiler inserts counted vmcnt before reg use).
#define PIPE_BARRIER() do {                                   \
    asm volatile("s_waitcnt lgkmcnt(0)" ::: "memory");        \
    __builtin_amdgcn_sched_barrier(0);                        \
    __builtin_amdgcn_s_barrier();                             \
    __builtin_amdgcn_sched_barrier(0);                        \
  } while (0)

// ------------------------------------------------------------------
// Pack concatenated weights [Wh | Wx] into fragment-major bf16 hi/lo,
// gate-interleaved n-permutation: srow(n) = (n&3)*1024 + (n>>6)*16 + ((n>>2)&15)
// pk[((nt*KS + ks)*2 + hilo)*512 + l*8 + e] = src[srow(nt*16+(l&15))][ks*32+(l>>4)*8+e]
// ------------------------------------------------------------------
__global__ __launch_bounds__(256)
void pack_w2(const float* __restrict__ Wh, const float* __restrict__ Wx,
             unsigned short* __restrict__ pk, int Kh, int Kx) {
  const int KS = (Kh + Kx) >> 5;
  const int idx = blockIdx.x * 256 + threadIdx.x;
  const int total = 256 * KS * 64;
  if (idx >= total) return;
  const int l = idx & 63;
  const int t2 = idx >> 6;
  const int ks = t2 % KS;
  const int nt = t2 / KS;
  const int n = (nt << 4) + (l & 15);
  const int srow = ((n & 3) << 10) + ((n >> 6) << 4) + ((n >> 2) & 15);
  const int col = (ks << 5) + ((l >> 4) << 3);
  const float* src = (col < Kh) ? (Wh + (size_t)srow * Kh + col)
                                : (Wx + (size_t)srow * Kx + (col - Kh));
  unsigned short hi[8], lo[8];
#pragma unroll
  for (int e = 0; e < 8; ++e) {
    const float v = src[e];
    const unsigned short h = f2bf(v);
    hi[e] = h;
    lo[e] = f2bf(v - bf2f(h));
  }
  const size_t base = (((size_t)nt * KS + ks) * 2) * 512 + (size_t)l * 8;
  *(uint4*)(pk + base) = *(const uint4*)hi;
  *(uint4*)(pk + base + 512) = *(const uint4*)lo;
}

// LDS buffer layout (64 KB per buffer, two buffers):
//  [0, 32768):      W block: nt*8192 + ksl*2048 + hilo*1024 + l*16
//  [32768, 49152):  A hi bf16: row*256 + ((unit16 ^ (row&15))<<4)   (64 rows x 128 k)
//  [49152, 65536):  A lo bf16 (same addressing)

__device__ __forceinline__ void comp_bf16(const char* buf, int ngoff, int arb, int l4, int l15,
                                          f32x4& acc0, f32x4& acc1) {
#pragma unroll
  for (int ksl = 0; ksl < 4; ++ksl) {
    const bf16x8 wh = *(const bf16x8*)(buf + ngoff + ksl * 2048);
    const bf16x8 wl = *(const bf16x8*)(buf + ngoff + ksl * 2048 + 1024);
    const int so = (((ksl << 2) + l4) ^ l15) << 4;
    const bf16x8 ah0 = *(const bf16x8*)(buf + arb + so);
    const bf16x8 al0 = *(const bf16x8*)(buf + arb + so + 16384);
    const bf16x8 ah1 = *(const bf16x8*)(buf + arb + so + 4096);
    const bf16x8 al1 = *(const bf16x8*)(buf + arb + so + 4096 + 16384);
    acc0 = __builtin_amdgcn_mfma_f32_16x16x32_bf16(ah0, wh, acc0, 0, 0, 0);
    acc0 = __builtin_amdgcn_mfma_f32_16x16x32_bf16(ah0, wl, acc0, 0, 0, 0);
    acc0 = __builtin_amdgcn_mfma_f32_16x16x32_bf16(al0, wh, acc0, 0, 0, 0);
    acc1 = __builtin_amdgcn_mfma_f32_16x16x32_bf16(ah1, wh, acc1, 0, 0, 0);
    acc1 = __builtin_amdgcn_mfma_f32_16x16x32_bf16(ah1, wl, acc1, 0, 0, 0);
    acc1 = __builtin_amdgcn_mfma_f32_16x16x32_bf16(al1, wh, acc1, 0, 0, 0);
  }
}

// ------------------------------------------------------------------
// Diagonal dual-layer step: WGs 0..127 run layer0 @ t, WGs 128..255 run
// layer1 @ t-1. 512 thr/WG. W AND A staged in LDS, double-buffered (128KB).
// x converted to bf16 hi/lo AT STAGING (uniform compute path).
// Raw s_barrier pipeline: global prefetch stays in flight across barriers.
// ------------------------------------------------------------------
__global__ __launch_bounds__(512, 1)
void step_dual(int t,
               const float* __restrict__ x,
               const unsigned short* __restrict__ pk0,
               const unsigned short* __restrict__ pk1,
               unsigned short* __restrict__ h0s0, unsigned short* __restrict__ h0s1,
               unsigned short* __restrict__ h1s0, unsigned short* __restrict__ h1s1,
               const float* __restrict__ bih0, const float* __restrict__ bhh0,
               const float* __restrict__ bih1, const float* __restrict__ bhh1,
               float* __restrict__ c0, float* __restrict__ c1) {
  __shared__ __align__(16) char lds0[65536];
  __shared__ __align__(16) char lds1[65536];
  const int bid = blockIdx.x;
  const int layer = bid >> 7;
  if (layer == 0 && t >= TT) return;
  if (layer == 1 && t < 1) return;
  const int lbid = bid & 127;
  const int jg = lbid & 63, bh = lbid >> 6;
  const int tid = threadIdx.x;
  const int wid = tid >> 6, l = tid & 63;
  const int mh = wid & 1, ng = wid >> 1;
  const int l15 = l & 15, l4 = l >> 4;
  const int nl = (ng << 4) + l15;

  // per-layer configuration
  const int KS = layer ? 64 : 48;
  const int NB = KS >> 2;            // 12 or 16 blocks of 4 k-slices
  const unsigned short* pk = layer ? pk1 : pk0;
  const unsigned short* a1;          // prev-h of own layer (hi base; lo at +LOOFF)
  const unsigned short* a2;          // layer1: h0[t-1]
  unsigned short* ho;
  float* cb;
  const float* bv0;
  const float* bv1;
  if (layer == 0) {
    a1 = (t & 1) ? h0s0 : h0s1;
    ho = (t & 1) ? h0s1 : h0s0;
    a2 = a1;
    cb = c0; bv0 = bih0; bv1 = bhh0;
  } else {
    const int u = t - 1;
    a1 = (u & 1) ? h1s0 : h1s1;
    ho = (u & 1) ? h1s1 : h1s0;
    a2 = (t & 1) ? h0s0 : h0s1;
    cb = c1; bv0 = bih1; bv1 = bhh1;
  }

  // staging maps: thread = (arow 0..63, aseg 0..7); units aseg & aseg+8
  const int arow = tid >> 3;
  const int aseg = tid & 7;
  const int swA = arow & 15;
  const size_t growA = (size_t)((bh << 6) + arow);
  const unsigned short* a1g = a1 + growA * HH;
  const unsigned short* a2g = a2 + growA * HH;
  const float* xg = x + (size_t)t * DD + growA * XROW;

  const unsigned short* pkc0 = pk + ((size_t)(jg * 4 + 0) * KS) * 1024 + (size_t)tid * 8;
  const unsigned short* pkc1 = pk + ((size_t)(jg * 4 + 1) * KS) * 1024 + (size_t)tid * 8;
  const unsigned short* pkc2 = pk + ((size_t)(jg * 4 + 2) * KS) * 1024 + (size_t)tid * 8;
  const unsigned short* pkc3 = pk + ((size_t)(jg * 4 + 3) * KS) * 1024 + (size_t)tid * 8;

  // LDS write offsets (bf16 hi/lo planes; same for h and converted-x)
  const int aw0 = 32768 + arow * 256 + ((aseg ^ swA) << 4);
  const int aw1 = 32768 + arow * 256 + (((aseg + 8) ^ swA) << 4);

  // LDS read offsets
  const int ngoff = ng * 8192 + l * 16;
  const int arb = 32768 + (mh * 32 + l15) * 256;

  f32x4 acc0 = (f32x4)(0.f), acc1 = (f32x4)(0.f);
  uint4 qw0, qw1, qw2, qw3, qa0, qa1, qa2, qa3;

#define LOADW(bb) do {                                        \
    qw0 = *(const uint4*)(pkc0 + (size_t)(bb) * 4096);        \
    qw1 = *(const uint4*)(pkc1 + (size_t)(bb) * 4096);        \
    qw2 = *(const uint4*)(pkc2 + (size_t)(bb) * 4096);        \
    qw3 = *(const uint4*)(pkc3 + (size_t)(bb) * 4096);        \
  } while (0)

  // h blocks: qa0 = hi unit aseg, qa1 = hi unit aseg+8, qa2/qa3 = lo units.
  // x blocks: qa0..qa3 = raw fp32 (converted at write time).
#define LOADA(bb) do {                                                          \
    if ((bb) < 8) {                                                             \
      const unsigned short* s_ = a1g + ((bb) << 7) + (size_t)aseg * 8;          \
      qa0 = *(const uint4*)s_;           qa1 = *(const uint4*)(s_ + 64);        \
      qa2 = *(const uint4*)(s_ + LOOFF); qa3 = *(const uint4*)(s_ + LOOFF + 64);\
    } else if (layer == 1) {                                                    \
      const unsigned short* s_ = a2g + (((bb) - 8) << 7) + (size_t)aseg * 8;    \
      qa0 = *(const uint4*)s_;           qa1 = *(const uint4*)(s_ + 64);        \
      qa2 = *(const uint4*)(s_ + LOOFF); qa3 = *(const uint4*)(s_ + LOOFF + 64);\
    } else {                                                                    \
      const float* s_ = xg + (((bb) - 8) << 7) + (size_t)aseg * 8;              \
      qa0 = *(const uint4*)s_;        qa1 = *(const uint4*)(s_ + 4);            \
      qa2 = *(const uint4*)(s_ + 64); qa3 = *(const uint4*)(s_ + 68);           \
    }                                                                           \
  } while (0)

#define WRITEB(buf, bb) do {                                                    \
    *(uint4*)((buf) + tid * 16)         = qw0;                                  \
    *(uint4*)((buf) + 8192 + tid * 16)  = qw1;                                  \
    *(uint4*)((buf) + 16384 + tid * 16) = qw2;                                  \
    *(uint4*)((buf) + 24576 + tid * 16) = qw3;                                  \
    if ((bb) < 8 || layer == 1) {                                               \
      *(uint4*)((buf) + aw0) = qa0; *(uint4*)((buf) + aw1) = qa1;               \
      *(uint4*)((buf) + aw0 + 16384) = qa2; *(uint4*)((buf) + aw1 + 16384) = qa3; \
    } else {                                                                    \
      bf16x8 xh0, xl0, xh1, xl1;                                                \
      split8(*(float4*)&qa0, *(float4*)&qa1, xh0, xl0);                         \
      split8(*(float4*)&qa2, *(float4*)&qa3, xh1, xl1);                         \
      *(bf16x8*)((buf) + aw0) = xh0; *(bf16x8*)((buf) + aw1) = xh1;             \
      *(bf16x8*)((buf) + aw0 + 16384) = xl0; *(bf16x8*)((buf) + aw1 + 16384) = xl1; \
    }                                                                           \
  } while (0)

  // prologue: stage block 0
  LOADW(0); LOADA(0);
  WRITEB(lds0, 0);
  PIPE_BARRIER();

  for (int b = 0; b < NB; ++b) {
    char* cur = (b & 1) ? lds1 : lds0;
    char* nxt = (b & 1) ? lds0 : lds1;
    if (b + 1 < NB) { LOADW(b + 1); LOADA(b + 1); }
    comp_bf16(cur, ngoff, arb, l4, l15, acc0, acc1);
    if (b + 1 < NB) WRITEB(nxt, b + 1);
    PIPE_BARRIER();
  }
#undef LOADW
#undef LOADA
#undef WRITEB

  // epilogue: bias + cell + h store (quad shfl gather: g = nl&3)
  const int n = (jg << 6) + nl;
  const int srow = ((n & 3) << 10) + ((n >> 6) << 4) + ((n >> 2) & 15);
  const float bn = bv0[srow] + bv1[srow];
  const int g = nl & 3;
  const int j = (jg << 4) + (nl >> 2);
  f32x4 accs[2] = {acc0, acc1};
#pragma unroll
  for (int mt = 0; mt < 2; ++mt) {
#pragma unroll
    for (int r = 0; r < 4; ++r) {
      const float v = accs[mt][r] + bn;
      const float v1 = __shfl_xor(v, 1);
      const float v2 = __shfl_xor(v, 2);
      const float v3 = __shfl_xor(v, 3);
      if (g == 0) {
        const int b = (bh << 6) + (mh << 5) + (mt << 4) + (l4 << 2) + r;
        const float si = sigmoid_fast(v);
        const float sf = sigmoid_fast(v1);
        const float tg = tanh_fast(v2);
        const float so = sigmoid_fast(v3);
        const size_t ci = (size_t)b * HH + j;
        const float cn = sf * cb[ci] + si * tg;
        cb[ci] = cn;
        const float h = so * tanh_fast(cn);
        const unsigned short hh = f2bf(h);
        ho[(size_t)b * HH + j] = hh;
        ho[LOOFF + (size_t)b * HH + j] = f2bf(h - bf2f(hh));
      }
    }
  }
}

// ------------------------------------------------------------------
// FC from hi/lo h slot
// ------------------------------------------------------------------
__global__ __launch_bounds__(256)
void fc_hilo(const unsigned short* __restrict__ hhi, const unsigned short* __restrict__ hlo,
             const float* __restrict__ fcw, const float* __restrict__ fcb,
             float* __restrict__ out) {
  const int gw = (int)((blockIdx.x * 256 + threadIdx.x) >> 6);
  const int lane = threadIdx.x & 63;
  const int b = gw / CO;
  const int n = gw - b * CO;
  const unsigned short* hp = hhi + (size_t)b * HH;
  const unsigned short* lp = hlo + (size_t)b * HH;
  const float* wp = fcw + (size_t)n * HH;
  float s = 0.f;
  for (int k = lane; k < HH; k += 64) s += (bf2f(hp[k]) + bf2f(lp[k])) * wp[k];
#pragma unroll
  for (int off = 32; off; off >>= 1) s += __shfl_down(s, off);
  if (lane == 0) out[b * CO + n] = s + fcb[n];
}

// ==================================================================
// Fallback fp32 path (round-2 kernels, used only if ws_size is small)
// ==================================================================
__global__ __launch_bounds__(256)
void gemm_bias(const float* __restrict__ A, long long sOut, long long sIn, int lt,
               const float* __restrict__ W,
               const float* __restrict__ b0, const float* __restrict__ b1,
               float* __restrict__ C, int N, int K) {
  __shared__ float as[16][64];
  __shared__ float wsh[16][64];
  const int tid = threadIdx.x;
  const int bm = blockIdx.y << 6;
  const int bn = blockIdx.x << 6;
  const int tr = (tid >> 4) << 2;
  const int tc = (tid & 15) << 2;
  const int lrow = tid >> 2;
  const int lk4 = (tid & 3) << 2;
  const int msk = (1 << lt) - 1;
  const int r = bm + lrow;
  const float* ap = A + (size_t)(r >> lt) * sOut + (size_t)(r & msk) * sIn + lk4;
  const float* wp = W + (size_t)(bn + lrow) * K + lk4;
  float acc[4][4] = {};
  for (int k0 = 0; k0 < K; k0 += 16) {
    const float4 av = *(const float4*)(ap + k0);
    const float4 wv = *(const float4*)(wp + k0);
    __syncthreads();
    as[lk4 + 0][lrow] = av.x; as[lk4 + 1][lrow] = av.y;
    as[lk4 + 2][lrow] = av.z; as[lk4 + 3][lrow] = av.w;
    wsh[lk4 + 0][lrow] = wv.x; wsh[lk4 + 1][lrow] = wv.y;
    wsh[lk4 + 2][lrow] = wv.z; wsh[lk4 + 3][lrow] = wv.w;
    __syncthreads();
#pragma unroll
    for (int k = 0; k < 16; ++k) {
      const float4 a = *(const float4*)&as[k][tr];
      const float4 b = *(const float4*)&wsh[k][tc];
      acc[0][0] += a.x * b.x; acc[0][1] += a.x * b.y; acc[0][2] += a.x * b.z; acc[0][3] += a.x * b.w;
      acc[1][0] += a.y * b.x; acc[1][1] += a.y * b.y; acc[1][2] += a.y * b.z; acc[1][3] += a.y * b.w;
      acc[2][0] += a.z * b.x; acc[2][1] += a.z * b.y; acc[2][2] += a.z * b.z; acc[2][3] += a.z * b.w;
      acc[3][0] += a.w * b.x; acc[3][1] += a.w * b.y; acc[3][2] += a.w * b.z; acc[3][3] += a.w * b.w;
    }
  }
  const float* bp0 = b0 + bn + tc;
  const float* bp1 = b1 + bn + tc;
#pragma unroll
  for (int i = 0; i < 4; ++i) {
    float* cp = C + (size_t)(bm + tr + i) * N + bn + tc;
#pragma unroll
    for (int j = 0; j < 4; ++j) cp[j] = acc[i][j] + bp0[j] + bp1[j];
  }
}

__global__ __launch_bounds__(256)
void lstm_step(const float* __restrict__ gx, long long gxstride,
               const float* __restrict__ whh,
               const float* __restrict__ hprev, long long pstride,
               float* __restrict__ hnext, long long nstride,
               float* __restrict__ cbuf) {
  __shared__ float hs[32][16];
  __shared__ float wsm[32][4][32];
  const int tid = threadIdx.x;
  const int jt = blockIdx.x << 5;
  const int bm = blockIdx.y << 4;
  const int col = tid & 31;
  const int rp = (tid >> 5) << 1;
  const int hr = tid >> 4;
  const int hk = (tid & 15) << 1;
  const int wrow = tid & 127;
  const int wg = wrow >> 5;
  const int wc = wrow & 31;
  const int wk = (tid >> 7) << 4;
  const float* wbase = whh + (size_t)(wg * HH + jt + wc) * HH + wk;
  const float* hbase = hprev + (size_t)(bm + hr) * pstride + hk;

  float acc[4][2] = {};
  for (int k0 = 0; k0 < HH; k0 += 32) {
    const float2 hv = *(const float2*)(hbase + k0);
    const float4 wv0 = *(const float4*)(wbase + k0);
    const float4 wv1 = *(const float4*)(wbase + k0 + 4);
    const float4 wv2 = *(const float4*)(wbase + k0 + 8);
    const float4 wv3 = *(const float4*)(wbase + k0 + 12);
    __syncthreads();
    hs[hk][hr] = hv.x; hs[hk + 1][hr] = hv.y;
    {
      const float wvv[16] = {wv0.x, wv0.y, wv0.z, wv0.w, wv1.x, wv1.y, wv1.z, wv1.w,
                             wv2.x, wv2.y, wv2.z, wv2.w, wv3.x, wv3.y, wv3.z, wv3.w};
#pragma unroll
      for (int i = 0; i < 16; ++i) wsm[wk + i][wg][wc] = wvv[i];
    }
    __syncthreads();
#pragma unroll
    for (int k = 0; k < 32; ++k) {
      const float2 a = *(const float2*)&hs[k][rp];
      const float wi = wsm[k][0][col];
      const float wf = wsm[k][1][col];
      const float wg_ = wsm[k][2][col];
      const float wo = wsm[k][3][col];
      acc[0][0] += a.x * wi;  acc[0][1] += a.y * wi;
      acc[1][0] += a.x * wf;  acc[1][1] += a.y * wf;
      acc[2][0] += a.x * wg_; acc[2][1] += a.y * wg_;
      acc[3][0] += a.x * wo;  acc[3][1] += a.y * wo;
    }
  }
#pragma unroll
  for (int rr = 0; rr < 2; ++rr) {
    const int b = bm + rp + rr;
    const int j = jt + col;
    const size_t gxo = (size_t)b * gxstride + j;
    const float gi = acc[0][rr] + gx[gxo];
    const float gf = acc[1][rr] + gx[gxo + HH];
    const float gg = acc[2][rr] + gx[gxo + 2 * HH];
    const float go = acc[3][rr] + gx[gxo + 3 * HH];
    const float si = 1.f / (1.f + expf(-gi));
    const float sf = 1.f / (1.f + expf(-gf));
    const float so = 1.f / (1.f + expf(-go));
    const size_t cidx = (size_t)b * HH + j;
    const float cn = sf * cbuf[cidx] + si * tanhf(gg);
    cbuf[cidx] = cn;
    hnext[(size_t)b * nstride + j] = so * tanhf(cn);
  }
}

__global__ __launch_bounds__(256)
void fc_kernel(const float* __restrict__ hlast, const float* __restrict__ fcw,
               const float* __restrict__ fcb, float* __restrict__ out) {
  const int gw = (int)((blockIdx.x * 256 + threadIdx.x) >> 6);
  const int lane = threadIdx.x & 63;
  const int b = gw / CO;
  const int n = gw - b * CO;
  const float* hp = hlast + (size_t)b * HH;
  const float* wp = fcw + (size_t)n * HH;
  float s = 0.f;
  for (int k = lane; k < HH; k += 64) s += hp[k] * wp[k];
#pragma unroll
  for (int off = 32; off; off >>= 1) s += __shfl_down(s, off);
  if (lane == 0) out[b * CO + n] = s + fcb[n];
}

// ==================================================================
extern "C" void kernel_launch(void* const* d_in, const int* in_sizes, int n_in,
                              void* d_out, int out_size, void* d_ws, size_t ws_size,
                              hipStream_t stream) {
  const float* x    = (const float*)d_in[0];
  const float* wih0 = (const float*)d_in[1];
  const float* whh0 = (const float*)d_in[2];
  const float* bih0 = (const float*)d_in[3];
  const float* bhh0 = (const float*)d_in[4];
  const float* wih1 = (const float*)d_in[5];
  const float* whh1 = (const float*)d_in[6];
  const float* bih1 = (const float*)d_in[7];
  const float* bhh1 = (const float*)d_in[8];
  const float* fcw  = (const float*)d_in[9];
  const float* fcb  = (const float*)d_in[10];
  float* out = (float*)d_out;

  // ---- MFMA-path workspace ----
  const size_t pk0B  = (size_t)256 * 48 * 1024 * 2;   // 25,165,824 B
  const size_t pk1B  = (size_t)256 * 64 * 1024 * 2;   // 33,554,432 B
  const size_t slotB = 2 * (size_t)BB * HH * 2;       // 524,288 B (hi+lo)
  const size_t cB    = (size_t)BB * HH * 4;           // 524,288 B
  const size_t needB = pk0B + pk1B + 4 * slotB + 2 * cB;  // 61,865,984 B

  if (needB <= ws_size) {
    char* p = (char*)d_ws;
    unsigned short* pk0  = (unsigned short*)p; p += pk0B;
    unsigned short* pk1  = (unsigned short*)p; p += pk1B;
    unsigned short* h0s0 = (unsigned short*)p; p += slotB;
    unsigned short* h1s0 = (unsigned short*)p; p += slotB;
    char* zblock = p;                         // h0s1, h1s1, c0, c1 (zeroed)
    unsigned short* h0s1 = (unsigned short*)p; p += slotB;
    unsigned short* h1s1 = (unsigned short*)p; p += slotB;
    float* c0 = (float*)p; p += cB;
    float* c1 = (float*)p; p += cB;

    hipMemsetAsync(zblock, 0, 2 * slotB + 2 * cB, stream);

    pack_w2<<<dim3((256 * 48 * 64) / 256), 256, 0, stream>>>(whh0, wih0, pk0, HH, DD);
    pack_w2<<<dim3((256 * 64 * 64) / 256), 256, 0, stream>>>(whh1, wih1, pk1, HH, HH);

    for (int t = 0; t <= TT; ++t) {
      step_dual<<<dim3(256), 512, 0, stream>>>(t, x, pk0, pk1,
                                               h0s0, h0s1, h1s0, h1s1,
                                               bih0, bhh0, bih1, bhh1, c0, c1);
    }

    // final u = 255 (odd) wrote slot[1] = h1s1
    fc_hilo<<<dim3((BB * CO * 64) / 256), 256, 0, stream>>>(h1s1, h1s1 + LOOFF,
                                                            fcw, fcb, out);
    return;
  }

  // ---------------- fallback fp32 path ----------------
  {
    int Tc2 = 64, lt2 = 6;
    while (Tc2 > 1) {
      size_t need = ((size_t)655360 * (size_t)Tc2 + 4u * 131072u + 1024u) * 4u;
      if (need <= ws_size) break;
      Tc2 >>= 1; --lt2;
    }
    float* ws  = (float*)d_ws;
    float* gxc = ws;
    float* hc  = gxc + (size_t)BB * Tc2 * G4H;
    float* c0  = hc + (size_t)BB * Tc2 * HH;
    float* c1  = c0 + (size_t)BB * HH;
    float* h2a = c1 + (size_t)BB * HH;
    float* h2b = h2a + (size_t)BB * HH;
    float* zb  = h2b + (size_t)BB * HH;

    hipMemsetAsync(zb, 0, HH * sizeof(float), stream);
    hipMemsetAsync(c0, 0, (size_t)BB * HH * sizeof(float), stream);
    hipMemsetAsync(c1, 0, (size_t)BB * HH * sizeof(float), stream);

    const dim3 gGemm(G4H / 64, (BB * Tc2) / 64);
    const dim3 gStep(HH / 32, BB / 16);
    const long long gxs = (long long)Tc2 * G4H;
    const long long hcs = (long long)Tc2 * HH;

    const int nChunks = TT / Tc2;
    for (int ci = 0; ci < nChunks; ++ci) {
      const int t0 = ci * Tc2;
      gemm_bias<<<gGemm, 256, 0, stream>>>(x + (size_t)t0 * DD, (long long)TT * DD,
                                           (long long)DD, lt2, wih0, bih0, bhh0,
                                           gxc, G4H, DD);
      for (int tl = 0; tl < Tc2; ++tl) {
        const int t = t0 + tl;
        const float* hprev;
        long long ps;
        if (t == 0) { hprev = zb; ps = 0; }
        else {
          const int ptl = (tl == 0) ? (Tc2 - 1) : (tl - 1);
          hprev = hc + (size_t)ptl * HH; ps = hcs;
        }
        lstm_step<<<gStep, 256, 0, stream>>>(gxc + (size_t)tl * G4H, gxs, whh0,
                                             hprev, ps, hc + (size_t)tl * HH, hcs, c0);
      }
      gemm_bias<<<gGemm, 256, 0, stream>>>(hc, hcs, (long long)HH, lt2,
                                           wih1, bih1, bhh1, gxc, G4H, HH);
      for (int tl = 0; tl < Tc2; ++tl) {
        const int t = t0 + tl;
        const float* hprev;
        long long ps;
        if (t == 0) { hprev = zb; ps = 0; }
        else { hprev = ((t - 1) & 1) ? h2b : h2a; ps = HH; }
        float* hnext = (t & 1) ? h2b : h2a;
        lstm_step<<<gStep, 256, 0, stream>>>(gxc + (size_t)tl * G4H, gxs, whh1,
                                             hprev, ps, hnext, HH, c1);
      }
    }
    fc_kernel<<<dim3((BB * CO * 64) / 256), 256, 0, stream>>>(h2b, fcw, fcb, out);
  }
}

// Round 9
// 7149.095 us; speedup vs baseline: 1.2685x; 1.0248x over previous
//
#include <hip/hip_runtime.h>
#include <math.h>

#define BB 128
#define TT 256
#define DD 512
#define HH 1024
#define G4H 4096
#define CO 7
#define XROW (TT * DD)      // x row stride per batch (fp32 elements)
#define LOOFF (BB * HH)     // offset of lo-plane within an h slot (elements)

typedef __attribute__((ext_vector_type(8))) short bf16x8;
typedef __attribute__((ext_vector_type(4))) float f32x4;

__device__ __forceinline__ unsigned short f2bf(float f) {
  unsigned int u = __float_as_uint(f);
  unsigned int r = (u + 0x7fffu + ((u >> 16) & 1u)) >> 16;
  return (unsigned short)r;
}
__device__ __forceinline__ float bf2f(unsigned short h) {
  return __uint_as_float(((unsigned int)h) << 16);
}
__device__ __forceinline__ float tanh_fast(float x) {
  x = fminf(fmaxf(x, -15.f), 15.f);
  const float e = __expf(2.f * x);
  return (e - 1.f) / (e + 1.f);
}
__device__ __forceinline__ float sigmoid_fast(float x) {
  return 1.f / (1.f + __expf(-x));
}
__device__ __forceinline__ void split8(float4 a, float4 b, bf16x8& hi, bf16x8& lo) {
  float f[8] = {a.x, a.y, a.z, a.w, b.x, b.y, b.z, b.w};
  unsigned short h8[8], l8[8];
#pragma unroll
  for (int e = 0; e < 8; ++e) {
    const unsigned short hh = f2bf(f[e]);
    h8[e] = hh;
    l8[e] = f2bf(f[e] - bf2f(hh));
  }
  hi = *(bf16x8*)h8;
  lo = *(bf16x8*)l8;
}

// raw barrier: drain only LDS queue (ds_write visibility), keep global loads
// in flight (no vmcnt drain — compiler inserts counted vmcnt before reg use).
#define PIPE_BARRIER() do {                                   \
    asm volatile("s_waitcnt lgkmcnt(0)" ::: "memory");        \
    __builtin_amdgcn_sched_barrier(0);                        \
    __builtin_amdgcn_s_barrier();                             \
    __builtin_amdgcn_sched_barrier(0);                        \
  } while (0)

// ------------------------------------------------------------------
// Pack concatenated weights [Wh | Wx] into fragment-major bf16 hi/lo,
// gate-interleaved n-permutation: srow(n) = (n&3)*1024 + (n>>6)*16 + ((n>>2)&15)
// pk[((nt*KS + ks)*2 + hilo)*512 + l*8 + e] = src[srow(nt*16+(l&15))][ks*32+(l>>4)*8+e]
// ------------------------------------------------------------------
__global__ __launch_bounds__(256)
void pack_w2(const float* __restrict__ Wh, const float* __restrict__ Wx,
             unsigned short* __restrict__ pk, int Kh, int Kx) {
  const int KS = (Kh + Kx) >> 5;
  const int idx = blockIdx.x * 256 + threadIdx.x;
  const int total = 256 * KS * 64;
  if (idx >= total) return;
  const int l = idx & 63;
  const int t2 = idx >> 6;
  const int ks = t2 % KS;
  const int nt = t2 / KS;
  const int n = (nt << 4) + (l & 15);
  const int srow = ((n & 3) << 10) + ((n >> 6) << 4) + ((n >> 2) & 15);
  const int col = (ks << 5) + ((l >> 4) << 3);
  const float* src = (col < Kh) ? (Wh + (size_t)srow * Kh + col)
                                : (Wx + (size_t)srow * Kx + (col - Kh));
  unsigned short hi[8], lo[8];
#pragma unroll
  for (int e = 0; e < 8; ++e) {
    const float v = src[e];
    const unsigned short h = f2bf(v);
    hi[e] = h;
    lo[e] = f2bf(v - bf2f(h));
  }
  const size_t base = (((size_t)nt * KS + ks) * 2) * 512 + (size_t)l * 8;
  *(uint4*)(pk + base) = *(const uint4*)hi;
  *(uint4*)(pk + base + 512) = *(const uint4*)lo;
}

// LDS buffer layout (64 KB per buffer, two buffers):
//  [0, 32768):      W block: nt*8192 + ksl*2048 + hilo*1024 + l*16
//  [32768, 49152):  A hi bf16: row*256 + ((unit16 ^ (row&15))<<4)   (64 rows x 128 k)
//  [49152, 65536):  A lo bf16 (same addressing)

__device__ __forceinline__ void comp_bf16(const char* buf, int ngoff, int arb, int l4, int l15,
                                          f32x4& acc0, f32x4& acc1) {
#pragma unroll
  for (int ksl = 0; ksl < 4; ++ksl) {
    const bf16x8 wh = *(const bf16x8*)(buf + ngoff + ksl * 2048);
    const bf16x8 wl = *(const bf16x8*)(buf + ngoff + ksl * 2048 + 1024);
    const int so = (((ksl << 2) + l4) ^ l15) << 4;
    const bf16x8 ah0 = *(const bf16x8*)(buf + arb + so);
    const bf16x8 al0 = *(const bf16x8*)(buf + arb + so + 16384);
    const bf16x8 ah1 = *(const bf16x8*)(buf + arb + so + 4096);
    const bf16x8 al1 = *(const bf16x8*)(buf + arb + so + 4096 + 16384);
    acc0 = __builtin_amdgcn_mfma_f32_16x16x32_bf16(ah0, wh, acc0, 0, 0, 0);
    acc0 = __builtin_amdgcn_mfma_f32_16x16x32_bf16(ah0, wl, acc0, 0, 0, 0);
    acc0 = __builtin_amdgcn_mfma_f32_16x16x32_bf16(al0, wh, acc0, 0, 0, 0);
    acc1 = __builtin_amdgcn_mfma_f32_16x16x32_bf16(ah1, wh, acc1, 0, 0, 0);
    acc1 = __builtin_amdgcn_mfma_f32_16x16x32_bf16(ah1, wl, acc1, 0, 0, 0);
    acc1 = __builtin_amdgcn_mfma_f32_16x16x32_bf16(al1, wh, acc1, 0, 0, 0);
  }
}

// ------------------------------------------------------------------
// Diagonal dual-layer step: WGs 0..127 run layer0 @ t, WGs 128..255 run
// layer1 @ t-1. 512 thr/WG. W AND A staged in LDS, double-buffered (128KB).
// x converted to bf16 hi/lo AT STAGING. Raw s_barrier pipeline with
// TWO-DEEP register prefetch: load->ds_write distance = 2 compute phases,
// covering L3/HBM latency.
// ------------------------------------------------------------------
__global__ __launch_bounds__(512, 1)
void step_dual(int t,
               const float* __restrict__ x,
               const unsigned short* __restrict__ pk0,
               const unsigned short* __restrict__ pk1,
               unsigned short* __restrict__ h0s0, unsigned short* __restrict__ h0s1,
               unsigned short* __restrict__ h1s0, unsigned short* __restrict__ h1s1,
               const float* __restrict__ bih0, const float* __restrict__ bhh0,
               const float* __restrict__ bih1, const float* __restrict__ bhh1,
               float* __restrict__ c0, float* __restrict__ c1) {
  __shared__ __align__(16) char lds0[65536];
  __shared__ __align__(16) char lds1[65536];
  const int bid = blockIdx.x;
  const int layer = bid >> 7;
  if (layer == 0 && t >= TT) return;
  if (layer == 1 && t < 1) return;
  const int lbid = bid & 127;
  const int jg = lbid & 63, bh = lbid >> 6;
  const int tid = threadIdx.x;
  const int wid = tid >> 6, l = tid & 63;
  const int mh = wid & 1, ng = wid >> 1;
  const int l15 = l & 15, l4 = l >> 4;
  const int nl = (ng << 4) + l15;

  // per-layer configuration
  const int KS = layer ? 64 : 48;
  const int NB = KS >> 2;            // 12 or 16 blocks of 4 k-slices (even)
  const unsigned short* pk = layer ? pk1 : pk0;
  const unsigned short* a1;          // prev-h of own layer (hi base; lo at +LOOFF)
  const unsigned short* a2;          // layer1: h0[t-1]
  unsigned short* ho;
  float* cb;
  const float* bv0;
  const float* bv1;
  if (layer == 0) {
    a1 = (t & 1) ? h0s0 : h0s1;
    ho = (t & 1) ? h0s1 : h0s0;
    a2 = a1;
    cb = c0; bv0 = bih0; bv1 = bhh0;
  } else {
    const int u = t - 1;
    a1 = (u & 1) ? h1s0 : h1s1;
    ho = (u & 1) ? h1s1 : h1s0;
    a2 = (t & 1) ? h0s0 : h0s1;
    cb = c1; bv0 = bih1; bv1 = bhh1;
  }

  // staging maps: thread = (arow 0..63, aseg 0..7); units aseg & aseg+8
  const int arow = tid >> 3;
  const int aseg = tid & 7;
  const int swA = arow & 15;
  const size_t growA = (size_t)((bh << 6) + arow);
  const unsigned short* a1g = a1 + growA * HH;
  const unsigned short* a2g = a2 + growA * HH;
  const float* xg = x + (size_t)t * DD + growA * XROW;

  const unsigned short* pkc0 = pk + ((size_t)(jg * 4 + 0) * KS) * 1024 + (size_t)tid * 8;
  const unsigned short* pkc1 = pk + ((size_t)(jg * 4 + 1) * KS) * 1024 + (size_t)tid * 8;
  const unsigned short* pkc2 = pk + ((size_t)(jg * 4 + 2) * KS) * 1024 + (size_t)tid * 8;
  const unsigned short* pkc3 = pk + ((size_t)(jg * 4 + 3) * KS) * 1024 + (size_t)tid * 8;

  // LDS write offsets (bf16 hi/lo planes; same for h and converted-x)
  const int aw0 = 32768 + arow * 256 + ((aseg ^ swA) << 4);
  const int aw1 = 32768 + arow * 256 + (((aseg + 8) ^ swA) << 4);

  // LDS read offsets
  const int ngoff = ng * 8192 + l * 16;
  const int arb = 32768 + (mh * 32 + l15) * 256;

  f32x4 acc0 = (f32x4)(0.f), acc1 = (f32x4)(0.f);
  // two named register banks (static indexing only — rule #20)
  uint4 wA0, wA1, wA2, wA3, aA0, aA1, aA2, aA3;
  uint4 wB0, wB1, wB2, wB3, aB0, aB1, aB2, aB3;

#define LOADW(bb, w0, w1, w2, w3) do {                        \
    w0 = *(const uint4*)(pkc0 + (size_t)(bb) * 4096);         \
    w1 = *(const uint4*)(pkc1 + (size_t)(bb) * 4096);         \
    w2 = *(const uint4*)(pkc2 + (size_t)(bb) * 4096);         \
    w3 = *(const uint4*)(pkc3 + (size_t)(bb) * 4096);         \
  } while (0)

  // h blocks: a0 = hi unit aseg, a1 = hi unit aseg+8, a2/a3 = lo units.
  // x blocks: a0..a3 = raw fp32 (converted at write time).
#define LOADA(bb, q0, q1, q2, q3) do {                                          \
    if ((bb) < 8) {                                                             \
      const unsigned short* s_ = a1g + ((bb) << 7) + (size_t)aseg * 8;          \
      q0 = *(const uint4*)s_;           q1 = *(const uint4*)(s_ + 64);          \
      q2 = *(const uint4*)(s_ + LOOFF); q3 = *(const uint4*)(s_ + LOOFF + 64);  \
    } else if (layer == 1) {                                                    \
      const unsigned short* s_ = a2g + (((bb) - 8) << 7) + (size_t)aseg * 8;    \
      q0 = *(const uint4*)s_;           q1 = *(const uint4*)(s_ + 64);          \
      q2 = *(const uint4*)(s_ + LOOFF); q3 = *(const uint4*)(s_ + LOOFF + 64);  \
    } else {                                                                    \
      const float* s_ = xg + (((bb) - 8) << 7) + (size_t)aseg * 8;              \
      q0 = *(const uint4*)s_;        q1 = *(const uint4*)(s_ + 4);              \
      q2 = *(const uint4*)(s_ + 64); q3 = *(const uint4*)(s_ + 68);             \
    }                                                                           \
  } while (0)

#define WRITEB(buf, bb, w0, w1, w2, w3, q0, q1, q2, q3) do {                    \
    *(uint4*)((buf) + tid * 16)         = w0;                                   \
    *(uint4*)((buf) + 8192 + tid * 16)  = w1;                                   \
    *(uint4*)((buf) + 16384 + tid * 16) = w2;                                   \
    *(uint4*)((buf) + 24576 + tid * 16) = w3;                                   \
    if ((bb) < 8 || layer == 1) {                                               \
      *(uint4*)((buf) + aw0) = q0; *(uint4*)((buf) + aw1) = q1;                 \
      *(uint4*)((buf) + aw0 + 16384) = q2; *(uint4*)((buf) + aw1 + 16384) = q3; \
    } else {                                                                    \
      bf16x8 xh0, xl0, xh1, xl1;                                                \
      split8(*(float4*)&q0, *(float4*)&q1, xh0, xl0);                           \
      split8(*(float4*)&q2, *(float4*)&q3, xh1, xl1);                           \
      *(bf16x8*)((buf) + aw0) = xh0; *(bf16x8*)((buf) + aw1) = xh1;             \
      *(bf16x8*)((buf) + aw0 + 16384) = xl0; *(bf16x8*)((buf) + aw1 + 16384) = xl1; \
    }                                                                           \
  } while (0)

  // prologue: block0 -> lds0 (immediate), block1 -> bankB (in flight)
  LOADW(0, wA0, wA1, wA2, wA3); LOADA(0, aA0, aA1, aA2, aA3);
  WRITEB(lds0, 0, wA0, wA1, wA2, wA3, aA0, aA1, aA2, aA3);
  LOADW(1, wB0, wB1, wB2, wB3); LOADA(1, aB0, aB1, aB2, aB3);
  PIPE_BARRIER();

  // steady state: 2 blocks per iteration, 2-deep prefetch.
  // bankA(b+2): issued [E] iter b, ds_written end of [O] iter b   (~2 phases)
  // bankB(b+3): issued [O] iter b, ds_written end of [E] iter b+2 (~2 phases)
  for (int b = 0; b < NB; b += 2) {
    // [E] phase: compute block b (lds0), commit bankB -> lds1
    if (b + 2 < NB) { LOADW(b + 2, wA0, wA1, wA2, wA3); LOADA(b + 2, aA0, aA1, aA2, aA3); }
    comp_bf16(lds0, ngoff, arb, l4, l15, acc0, acc1);
    WRITEB(lds1, b + 1, wB0, wB1, wB2, wB3, aB0, aB1, aB2, aB3);
    PIPE_BARRIER();
    // [O] phase: compute block b+1 (lds1), commit bankA -> lds0
    if (b + 3 < NB) { LOADW(b + 3, wB0, wB1, wB2, wB3); LOADA(b + 3, aB0, aB1, aB2, aB3); }
    comp_bf16(lds1, ngoff, arb, l4, l15, acc0, acc1);
    if (b + 2 < NB) WRITEB(lds0, b + 2, wA0, wA1, wA2, wA3, aA0, aA1, aA2, aA3);
    PIPE_BARRIER();
  }
#undef LOADW
#undef LOADA
#undef WRITEB

  // epilogue: bias + cell + h store (quad shfl gather: g = nl&3)
  const int n = (jg << 6) + nl;
  const int srow = ((n & 3) << 10) + ((n >> 6) << 4) + ((n >> 2) & 15);
  const float bn = bv0[srow] + bv1[srow];
  const int g = nl & 3;
  const int j = (jg << 4) + (nl >> 2);
  f32x4 accs[2] = {acc0, acc1};
#pragma unroll
  for (int mt = 0; mt < 2; ++mt) {
#pragma unroll
    for (int r = 0; r < 4; ++r) {
      const float v = accs[mt][r] + bn;
      const float v1 = __shfl_xor(v, 1);
      const float v2 = __shfl_xor(v, 2);
      const float v3 = __shfl_xor(v, 3);
      if (g == 0) {
        const int b = (bh << 6) + (mh << 5) + (mt << 4) + (l4 << 2) + r;
        const float si = sigmoid_fast(v);
        const float sf = sigmoid_fast(v1);
        const float tg = tanh_fast(v2);
        const float so = sigmoid_fast(v3);
        const size_t ci = (size_t)b * HH + j;
        const float cn = sf * cb[ci] + si * tg;
        cb[ci] = cn;
        const float h = so * tanh_fast(cn);
        const unsigned short hh = f2bf(h);
        ho[(size_t)b * HH + j] = hh;
        ho[LOOFF + (size_t)b * HH + j] = f2bf(h - bf2f(hh));
      }
    }
  }
}

// ------------------------------------------------------------------
// FC from hi/lo h slot
// ------------------------------------------------------------------
__global__ __launch_bounds__(256)
void fc_hilo(const unsigned short* __restrict__ hhi, const unsigned short* __restrict__ hlo,
             const float* __restrict__ fcw, const float* __restrict__ fcb,
             float* __restrict__ out) {
  const int gw = (int)((blockIdx.x * 256 + threadIdx.x) >> 6);
  const int lane = threadIdx.x & 63;
  const int b = gw / CO;
  const int n = gw - b * CO;
  const unsigned short* hp = hhi + (size_t)b * HH;
  const unsigned short* lp = hlo + (size_t)b * HH;
  const float* wp = fcw + (size_t)n * HH;
  float s = 0.f;
  for (int k = lane; k < HH; k += 64) s += (bf2f(hp[k]) + bf2f(lp[k])) * wp[k];
#pragma unroll
  for (int off = 32; off; off >>= 1) s += __shfl_down(s, off);
  if (lane == 0) out[b * CO + n] = s + fcb[n];
}

// ==================================================================
// Fallback fp32 path (round-2 kernels, used only if ws_size is small)
// ==================================================================
__global__ __launch_bounds__(256)
void gemm_bias(const float* __restrict__ A, long long sOut, long long sIn, int lt,
               const float* __restrict__ W,
               const float* __restrict__ b0, const float* __restrict__ b1,
               float* __restrict__ C, int N, int K) {
  __shared__ float as[16][64];
  __shared__ float wsh[16][64];
  const int tid = threadIdx.x;
  const int bm = blockIdx.y << 6;
  const int bn = blockIdx.x << 6;
  const int tr = (tid >> 4) << 2;
  const int tc = (tid & 15) << 2;
  const int lrow = tid >> 2;
  const int lk4 = (tid & 3) << 2;
  const int msk = (1 << lt) - 1;
  const int r = bm + lrow;
  const float* ap = A + (size_t)(r >> lt) * sOut + (size_t)(r & msk) * sIn + lk4;
  const float* wp = W + (size_t)(bn + lrow) * K + lk4;
  float acc[4][4] = {};
  for (int k0 = 0; k0 < K; k0 += 16) {
    const float4 av = *(const float4*)(ap + k0);
    const float4 wv = *(const float4*)(wp + k0);
    __syncthreads();
    as[lk4 + 0][lrow] = av.x; as[lk4 + 1][lrow] = av.y;
    as[lk4 + 2][lrow] = av.z; as[lk4 + 3][lrow] = av.w;
    wsh[lk4 + 0][lrow] = wv.x; wsh[lk4 + 1][lrow] = wv.y;
    wsh[lk4 + 2][lrow] = wv.z; wsh[lk4 + 3][lrow] = wv.w;
    __syncthreads();
#pragma unroll
    for (int k = 0; k < 16; ++k) {
      const float4 a = *(const float4*)&as[k][tr];
      const float4 b = *(const float4*)&wsh[k][tc];
      acc[0][0] += a.x * b.x; acc[0][1] += a.x * b.y; acc[0][2] += a.x * b.z; acc[0][3] += a.x * b.w;
      acc[1][0] += a.y * b.x; acc[1][1] += a.y * b.y; acc[1][2] += a.y * b.z; acc[1][3] += a.y * b.w;
      acc[2][0] += a.z * b.x; acc[2][1] += a.z * b.y; acc[2][2] += a.z * b.z; acc[2][3] += a.z * b.w;
      acc[3][0] += a.w * b.x; acc[3][1] += a.w * b.y; acc[3][2] += a.w * b.z; acc[3][3] += a.w * b.w;
    }
  }
  const float* bp0 = b0 + bn + tc;
  const float* bp1 = b1 + bn + tc;
#pragma unroll
  for (int i = 0; i < 4; ++i) {
    float* cp = C + (size_t)(bm + tr + i) * N + bn + tc;
#pragma unroll
    for (int j = 0; j < 4; ++j) cp[j] = acc[i][j] + bp0[j] + bp1[j];
  }
}

__global__ __launch_bounds__(256)
void lstm_step(const float* __restrict__ gx, long long gxstride,
               const float* __restrict__ whh,
               const float* __restrict__ hprev, long long pstride,
               float* __restrict__ hnext, long long nstride,
               float* __restrict__ cbuf) {
  __shared__ float hs[32][16];
  __shared__ float wsm[32][4][32];
  const int tid = threadIdx.x;
  const int jt = blockIdx.x << 5;
  const int bm = blockIdx.y << 4;
  const int col = tid & 31;
  const int rp = (tid >> 5) << 1;
  const int hr = tid >> 4;
  const int hk = (tid & 15) << 1;
  const int wrow = tid & 127;
  const int wg = wrow >> 5;
  const int wc = wrow & 31;
  const int wk = (tid >> 7) << 4;
  const float* wbase = whh + (size_t)(wg * HH + jt + wc) * HH + wk;
  const float* hbase = hprev + (size_t)(bm + hr) * pstride + hk;

  float acc[4][2] = {};
  for (int k0 = 0; k0 < HH; k0 += 32) {
    const float2 hv = *(const float2*)(hbase + k0);
    const float4 wv0 = *(const float4*)(wbase + k0);
    const float4 wv1 = *(const float4*)(wbase + k0 + 4);
    const float4 wv2 = *(const float4*)(wbase + k0 + 8);
    const float4 wv3 = *(const float4*)(wbase + k0 + 12);
    __syncthreads();
    hs[hk][hr] = hv.x; hs[hk + 1][hr] = hv.y;
    {
      const float wvv[16] = {wv0.x, wv0.y, wv0.z, wv0.w, wv1.x, wv1.y, wv1.z, wv1.w,
                             wv2.x, wv2.y, wv2.z, wv2.w, wv3.x, wv3.y, wv3.z, wv3.w};
#pragma unroll
      for (int i = 0; i < 16; ++i) wsm[wk + i][wg][wc] = wvv[i];
    }
    __syncthreads();
#pragma unroll
    for (int k = 0; k < 32; ++k) {
      const float2 a = *(const float2*)&hs[k][rp];
      const float wi = wsm[k][0][col];
      const float wf = wsm[k][1][col];
      const float wg_ = wsm[k][2][col];
      const float wo = wsm[k][3][col];
      acc[0][0] += a.x * wi;  acc[0][1] += a.y * wi;
      acc[1][0] += a.x * wf;  acc[1][1] += a.y * wf;
      acc[2][0] += a.x * wg_; acc[2][1] += a.y * wg_;
      acc[3][0] += a.x * wo;  acc[3][1] += a.y * wo;
    }
  }
#pragma unroll
  for (int rr = 0; rr < 2; ++rr) {
    const int b = bm + rp + rr;
    const int j = jt + col;
    const size_t gxo = (size_t)b * gxstride + j;
    const float gi = acc[0][rr] + gx[gxo];
    const float gf = acc[1][rr] + gx[gxo + HH];
    const float gg = acc[2][rr] + gx[gxo + 2 * HH];
    const float go = acc[3][rr] + gx[gxo + 3 * HH];
    const float si = 1.f / (1.f + expf(-gi));
    const float sf = 1.f / (1.f + expf(-gf));
    const float so = 1.f / (1.f + expf(-go));
    const size_t cidx = (size_t)b * HH + j;
    const float cn = sf * cbuf[cidx] + si * tanhf(gg);
    cbuf[cidx] = cn;
    hnext[(size_t)b * nstride + j] = so * tanhf(cn);
  }
}

__global__ __launch_bounds__(256)
void fc_kernel(const float* __restrict__ hlast, const float* __restrict__ fcw,
               const float* __restrict__ fcb, float* __restrict__ out) {
  const int gw = (int)((blockIdx.x * 256 + threadIdx.x) >> 6);
  const int lane = threadIdx.x & 63;
  const int b = gw / CO;
  const int n = gw - b * CO;
  const float* hp = hlast + (size_t)b * HH;
  const float* wp = fcw + (size_t)n * HH;
  float s = 0.f;
  for (int k = lane; k < HH; k += 64) s += hp[k] * wp[k];
#pragma unroll
  for (int off = 32; off; off >>= 1) s += __shfl_down(s, off);
  if (lane == 0) out[b * CO + n] = s + fcb[n];
}

// ==================================================================
extern "C" void kernel_launch(void* const* d_in, const int* in_sizes, int n_in,
                              void* d_out, int out_size, void* d_ws, size_t ws_size,
                              hipStream_t stream) {
  const float* x    = (const float*)d_in[0];
  const float* wih0 = (const float*)d_in[1];
  const float* whh0 = (const float*)d_in[2];
  const float* bih0 = (const float*)d_in[3];
  const float* bhh0 = (const float*)d_in[4];
  const float* wih1 = (const float*)d_in[5];
  const float* whh1 = (const float*)d_in[6];
  const float* bih1 = (const float*)d_in[7];
  const float* bhh1 = (const float*)d_in[8];
  const float* fcw  = (const float*)d_in[9];
  const float* fcb  = (const float*)d_in[10];
  float* out = (float*)d_out;

  // ---- MFMA-path workspace ----
  const size_t pk0B  = (size_t)256 * 48 * 1024 * 2;   // 25,165,824 B
  const size_t pk1B  = (size_t)256 * 64 * 1024 * 2;   // 33,554,432 B
  const size_t slotB = 2 * (size_t)BB * HH * 2;       // 524,288 B (hi+lo)
  const size_t cB    = (size_t)BB * HH * 4;           // 524,288 B
  const size_t needB = pk0B + pk1B + 4 * slotB + 2 * cB;  // 61,865,984 B

  if (needB <= ws_size) {
    char* p = (char*)d_ws;
    unsigned short* pk0  = (unsigned short*)p; p += pk0B;
    unsigned short* pk1  = (unsigned short*)p; p += pk1B;
    unsigned short* h0s0 = (unsigned short*)p; p += slotB;
    unsigned short* h1s0 = (unsigned short*)p; p += slotB;
    char* zblock = p;                         // h0s1, h1s1, c0, c1 (zeroed)
    unsigned short* h0s1 = (unsigned short*)p; p += slotB;
    unsigned short* h1s1 = (unsigned short*)p; p += slotB;
    float* c0 = (float*)p; p += cB;
    float* c1 = (float*)p; p += cB;

    hipMemsetAsync(zblock, 0, 2 * slotB + 2 * cB, stream);

    pack_w2<<<dim3((256 * 48 * 64) / 256), 256, 0, stream>>>(whh0, wih0, pk0, HH, DD);
    pack_w2<<<dim3((256 * 64 * 64) / 256), 256, 0, stream>>>(whh1, wih1, pk1, HH, HH);

    for (int t = 0; t <= TT; ++t) {
      step_dual<<<dim3(256), 512, 0, stream>>>(t, x, pk0, pk1,
                                               h0s0, h0s1, h1s0, h1s1,
                                               bih0, bhh0, bih1, bhh1, c0, c1);
    }

    // final u = 255 (odd) wrote slot[1] = h1s1
    fc_hilo<<<dim3((BB * CO * 64) / 256), 256, 0, stream>>>(h1s1, h1s1 + LOOFF,
                                                            fcw, fcb, out);
    return;
  }

  // ---------------- fallback fp32 path ----------------
  {
    int Tc2 = 64, lt2 = 6;
    while (Tc2 > 1) {
      size_t need = ((size_t)655360 * (size_t)Tc2 + 4u * 131072u + 1024u) * 4u;
      if (need <= ws_size) break;
      Tc2 >>= 1; --lt2;
    }
    float* ws  = (float*)d_ws;
    float* gxc = ws;
    float* hc  = gxc + (size_t)BB * Tc2 * G4H;
    float* c0  = hc + (size_t)BB * Tc2 * HH;
    float* c1  = c0 + (size_t)BB * HH;
    float* h2a = c1 + (size_t)BB * HH;
    float* h2b = h2a + (size_t)BB * HH;
    float* zb  = h2b + (size_t)BB * HH;

    hipMemsetAsync(zb, 0, HH * sizeof(float), stream);
    hipMemsetAsync(c0, 0, (size_t)BB * HH * sizeof(float), stream);
    hipMemsetAsync(c1, 0, (size_t)BB * HH * sizeof(float), stream);

    const dim3 gGemm(G4H / 64, (BB * Tc2) / 64);
    const dim3 gStep(HH / 32, BB / 16);
    const long long gxs = (long long)Tc2 * G4H;
    const long long hcs = (long long)Tc2 * HH;

    const int nChunks = TT / Tc2;
    for (int ci = 0; ci < nChunks; ++ci) {
      const int t0 = ci * Tc2;
      gemm_bias<<<gGemm, 256, 0, stream>>>(x + (size_t)t0 * DD, (long long)TT * DD,
                                           (long long)DD, lt2, wih0, bih0, bhh0,
                                           gxc, G4H, DD);
      for (int tl = 0; tl < Tc2; ++tl) {
        const int t = t0 + tl;
        const float* hprev;
        long long ps;
        if (t == 0) { hprev = zb; ps = 0; }
        else {
          const int ptl = (tl == 0) ? (Tc2 - 1) : (tl - 1);
          hprev = hc + (size_t)ptl * HH; ps = hcs;
        }
        lstm_step<<<gStep, 256, 0, stream>>>(gxc + (size_t)tl * G4H, gxs, whh0,
                                             hprev, ps, hc + (size_t)tl * HH, hcs, c0);
      }
      gemm_bias<<<gGemm, 256, 0, stream>>>(hc, hcs, (long long)HH, lt2,
                                           wih1, bih1, bhh1, gxc, G4H, HH);
      for (int tl = 0; tl < Tc2; ++tl) {
        const int t = t0 + tl;
        const float* hprev;
        long long ps;
        if (t == 0) { hprev = zb; ps = 0; }
        else { hprev = ((t - 1) & 1) ? h2b : h2a; ps = HH; }
        float* hnext = (t & 1) ? h2b : h2a;
        lstm_step<<<gStep, 256, 0, stream>>>(gxc + (size_t)tl * G4H, gxs, whh1,
                                             hprev, ps, hnext, HH, c1);
      }
    }
    fc_kernel<<<dim3((BB * CO * 64) / 256), 256, 0, stream>>>(h2b, fcw, fcb, out);
  }
}